// Round 2
// baseline (193.371 us; speedup 1.0000x reference)
//
#include <hip/hip_runtime.h>

// Problem constants
static constexpr int BL = 128;          // B*L = 4*32
// ws layout (float offsets)
static constexpr int OFF_ARE  = 2048;     // A = Wp1*Wb, [96][64]
static constexpr int OFF_AIM  = 8192;
static constexpr int OFF_WRE  = 14336;    // Wcp = Wc*Wp2, [64][96]
static constexpr int OFF_WIM  = 20480;
static constexpr int OFF_LRE  = 26624;    // lambda, [96][32]
static constexpr int OFF_LIM  = 29696;
static constexpr int OFF_GAM  = 32768;    // gamma, [96][32]
static constexpr int OFF_BH0R = 35840;    // 1024*Wp1*bb, [96]
static constexpr int OFF_BH0I = 35936;
static constexpr int OFF_BRR  = 36032;    // Re(Wc*bp2)+bc_r, [64]
static constexpr int OFF_QF   = 36096;    // qF [8192 planes][32 h] cplx
static constexpr int OFF_Y    = 560384;   // S (post-scan) [128][96][32] cplx

// Fused: blocks [0,2048) do per-plane anti-diagonal sums + 32-pt DFT;
// blocks [2048, 2109) do the parameter precompute (independent work).
__global__ __launch_bounds__(256) void kA(
    const float* __restrict__ x,
    const float* __restrict__ params_log,
    const float* __restrict__ Wb_r, const float* __restrict__ Wb_i,
    const float* __restrict__ bb_r, const float* __restrict__ bb_i,
    const float* __restrict__ Wp1_r, const float* __restrict__ Wp1_i,
    const float* __restrict__ Wp2_r, const float* __restrict__ Wp2_i,
    const float* __restrict__ Wc_r, const float* __restrict__ Wc_i,
    const float* __restrict__ bp2_r, const float* __restrict__ bp2_i,
    const float* __restrict__ bc_r, float* __restrict__ ws) {
  if (blockIdx.x < 2048) {
    __shared__ float pl[4][1024];
    __shared__ float qsh[4][32];
    __shared__ float ct[32], st[32];
    int wave = threadIdx.x >> 6, lane = threadIdx.x & 63;
    if (threadIdx.x < 32) {
      float sv, cv;
      sincosf((float)threadIdx.x * 0.19634954084936207f, &sv, &cv);
      ct[threadIdx.x] = cv;
      st[threadIdx.x] = sv;
    }
    int plane = blockIdx.x * 4 + wave;  // < 8192
    const float4* xp = (const float4*)(x + (size_t)plane * 1024);
    float4* pl4 = (float4*)pl[wave];
#pragma unroll
    for (int j = 0; j < 4; ++j) pl4[j * 64 + lane] = xp[j * 64 + lane];
    __syncthreads();
    int s = lane & 31, halfw = lane >> 5;
    float acc = 0.f;
#pragma unroll
    for (int u0 = 0; u0 < 16; ++u0) {
      int u = halfw * 16 + u0;
      acc += pl[wave][u * 32 + ((s - u) & 31)];
    }
    acc += __shfl_xor(acc, 32);
    if (lane < 32) qsh[wave][lane] = acc;
    __syncthreads();
    int h = lane & 31;
    const float* T = (lane < 32) ? ct : st;
    float sum = 0.f;
    int m = 0;
#pragma unroll
    for (int s2 = 0; s2 < 32; ++s2) {
      sum += qsh[wave][s2] * T[m];
      m = (m + h) & 31;
    }
    if (lane >= 32) sum = -sum;  // imag part of e^{-i...}
    ws[OFF_QF + (size_t)plane * 64 + h * 2 + (lane < 32 ? 0 : 1)] = sum;
  } else {
    int tid = (int)(blockIdx.x - 2048) * 256 + threadIdx.x;
    if (tid < 3072) {
      int i = tid;  // c*32+h
      float nu = expf(params_log[i]);
      float th = expf(params_log[3072 + i]);
      float g  = expf(params_log[6144 + i]);
      float rr = expf(-nu);
      ws[OFF_LRE + i] = rr * cosf(th);
      ws[OFF_LIM + i] = rr * sinf(th);
      ws[OFF_GAM + i] = g;
    } else if (tid < 9216) {
      int i = tid - 3072;  // A[c][e]
      int c = i >> 6, e = i & 63;
      float are = 0.f, aim = 0.f;
      for (int k = 0; k < 96; ++k) {
        float pr = Wp1_r[c * 96 + k], pi = Wp1_i[c * 96 + k];
        float wr = Wb_r[k * 64 + e], wi = Wb_i[k * 64 + e];
        are += pr * wr - pi * wi;
        aim += pr * wi + pi * wr;
      }
      ws[OFF_ARE + i] = are;
      ws[OFF_AIM + i] = aim;
    } else if (tid < 15360) {
      int i = tid - 9216;  // Wcp[e][c]
      int e = i / 96, c = i - e * 96;
      float are = 0.f, aim = 0.f;
      for (int k = 0; k < 96; ++k) {
        float wr = Wc_r[e * 96 + k], wi = Wc_i[e * 96 + k];
        float pr = Wp2_r[k * 96 + c], pi = Wp2_i[k * 96 + c];
        are += wr * pr - wi * pi;
        aim += wr * pi + wi * pr;
      }
      ws[OFF_WRE + i] = are;
      ws[OFF_WIM + i] = aim;
    } else if (tid < 15456) {
      int c = tid - 15360;  // 1024 * (Wp1 . bb)[c]
      float re = 0.f, im = 0.f;
      for (int k = 0; k < 96; ++k) {
        float pr = Wp1_r[c * 96 + k], pi = Wp1_i[c * 96 + k];
        float br = bb_r[k], bi = bb_i[k];
        re += pr * br - pi * bi;
        im += pr * bi + pi * br;
      }
      ws[OFF_BH0R + c] = 1024.f * re;
      ws[OFF_BH0I + c] = 1024.f * im;
    } else if (tid < 15520) {
      int e = tid - 15456;  // Re(Wc . bp2)[e] + bc_r[e]
      float re = 0.f;
      for (int k = 0; k < 96; ++k)
        re += Wc_r[e * 96 + k] * bp2_r[k] - Wc_i[e * 96 + k] * bp2_i[k];
      ws[OFF_BRR + e] = re + bc_r[e];
    }
  }
}

// Fused mix1 + decay-scan. Block = (b, h, c-half): for fixed h the whole
// l x c plane depends only on the qF[b,:,:,h] slice (16 KB, LDS). Compute
// Y = gamma*(A qF + bias) into LDS, scan over l in LDS, write post-scan S.
__global__ __launch_bounds__(256) void kBC(float* __restrict__ ws,
                                           const float* __restrict__ mask,
                                           const float* __restrict__ bp1_r,
                                           const float* __restrict__ bp1_i) {
  __shared__ float qre[32][65], qim[32][65];   // [l][e], pad -> conflict-free
  __shared__ float Yre[48][33], Yim[48][33];   // [c_loc][l]
  __shared__ float msh[32];
  int b = blockIdx.x >> 6;           // 4
  int h = (blockIdx.x >> 1) & 31;    // 32
  int ch = blockIdx.x & 1;           // c-half: c in [ch*48, ch*48+48)
  const float2* qF2 = (const float2*)(ws + OFF_QF);
  for (int i = threadIdx.x; i < 2048; i += 256) {
    int l = i >> 6, e = i & 63;
    float2 v = qF2[(size_t)(b * 2048 + l * 64 + e) * 32 + h];
    qre[l][e] = v.x;
    qim[l][e] = v.y;
  }
  if (threadIdx.x < 32) msh[threadIdx.x] = mask[b * 32 + threadIdx.x];
  __syncthreads();
  // mix1: thread = (l = t&31, cg = t>>5); 6 c's per thread.
  int l = threadIdx.x & 31, cg = threadIdx.x >> 5;
  int cbase = ch * 48 + cg * 6;
  float yr[6] = {0.f, 0.f, 0.f, 0.f, 0.f, 0.f};
  float yi[6] = {0.f, 0.f, 0.f, 0.f, 0.f, 0.f};
#pragma unroll 8
  for (int e = 0; e < 64; ++e) {
    float qr = qre[l][e], qi_ = qim[l][e];
#pragma unroll
    for (int k = 0; k < 6; ++k) {
      int c = cbase + k;
      float ar = ws[OFF_ARE + c * 64 + e];
      float ai = ws[OFF_AIM + c * 64 + e];
      yr[k] += ar * qr - ai * qi_;
      yi[k] += ar * qi_ + ai * qr;
    }
  }
#pragma unroll
  for (int k = 0; k < 6; ++k) {
    int c = cbase + k;
    float re = yr[k] + bp1_r[c];
    float im = yi[k] + bp1_i[c];
    if (h == 0) { re += ws[OFF_BH0R + c]; im += ws[OFF_BH0I + c]; }
    float g = ws[OFF_GAM + c * 32 + h];
    Yre[cg * 6 + k][l] = g * re;
    Yim[cg * 6 + k][l] = g * im;
  }
  __syncthreads();
  // scan over l per chain c (48 chains, block-local), write S to global.
  if (threadIdx.x < 48) {
    int cl = threadIdx.x, c = ch * 48 + cl;
    float lr = ws[OFF_LRE + c * 32 + h], li = ws[OFF_LIM + c * 32 + h];
    float2* Sg = (float2*)(ws + OFF_Y);
    float sr = Yre[cl][0], si = Yim[cl][0];
    Sg[((size_t)(b * 32 + 0) * 96 + c) * 32 + h] = make_float2(sr, si);
    for (int l2 = 1; l2 < 32; ++l2) {
      float mk = msh[l2 - 1];
      float cr = mk * (lr * sr - li * si);
      float ci = mk * (lr * si + li * sr);
      sr = Yre[cl][l2] + cr;
      si = Yim[cl][l2] + ci;
      Sg[((size_t)(b * 32 + l2) * 96 + c) * 32 + h] = make_float2(sr, si);
    }
  }
}

// Fused mix2 + iDFT + LN stats + final output. Block = (bl, e-half); each
// block computes the FULL 64-e V/R (duplicate compute -> complete LN stats
// locally, no cross-block exchange), then writes its contiguous out half.
// R never leaves LDS.
__global__ __launch_bounds__(256) void kDE(const float* __restrict__ x,
                                           const float* __restrict__ lnw,
                                           const float* __restrict__ lnb,
                                           float* __restrict__ ws,
                                           float* __restrict__ out) {
  __shared__ float2 S[96][33];
  __shared__ float2 V[64][33];
  __shared__ float Rsh[64][32];
  __shared__ float ct[32], st[32];
  __shared__ float red[8];
  __shared__ float stats[2];
  int bl = blockIdx.x >> 1, half = blockIdx.x & 1;
  const float2* Sg = (const float2*)(ws + OFF_Y) + (size_t)bl * 3072;
  for (int i = threadIdx.x; i < 3072; i += 256) S[i >> 5][i & 31] = Sg[i];
  if (threadIdx.x < 32) {
    float sv, cv;
    sincosf((float)threadIdx.x * 0.19634954084936207f, &sv, &cv);
    ct[threadIdx.x] = cv;
    st[threadIdx.x] = sv;
  }
  __syncthreads();
  // mix2 over ALL 64 e: thread = (h = t&31, g = t>>5), e = g + 8k.
  int h = threadIdx.x & 31, g = threadIdx.x >> 5;
  float vr[8] = {0.f, 0.f, 0.f, 0.f, 0.f, 0.f, 0.f, 0.f};
  float vi[8] = {0.f, 0.f, 0.f, 0.f, 0.f, 0.f, 0.f, 0.f};
#pragma unroll 4
  for (int c = 0; c < 96; ++c) {
    float2 s = S[c][h];
#pragma unroll
    for (int k = 0; k < 8; ++k) {
      int e = g + k * 8;
      float wr = ws[OFF_WRE + e * 96 + c];
      float wi = ws[OFF_WIM + e * 96 + c];
      vr[k] += wr * s.x - wi * s.y;
      vi[k] += wr * s.y + wi * s.x;
    }
  }
#pragma unroll
  for (int k = 0; k < 8; ++k) V[g + k * 8][h] = make_float2(vr[k], vi[k]);
  __syncthreads();
  // iDFT: R[e,s] = Re(sum_h V[e,h] e^{+i..})/1024 + bR[e]; full stats.
  float sum = 0.f, sumsq = 0.f;
  int s2 = threadIdx.x & 31;
#pragma unroll
  for (int k = 0; k < 8; ++k) {
    int el = k * 8 + (threadIdx.x >> 5);
    float acc = 0.f;
    int m = 0;
#pragma unroll
    for (int hh = 0; hh < 32; ++hh) {
      float2 v = V[el][hh];
      acc += v.x * ct[m] - v.y * st[m];
      m = (m + s2) & 31;
    }
    float r = acc * (1.0f / 1024.0f) + ws[OFF_BRR + el];
    Rsh[el][s2] = r;
    sum += r;
    sumsq += r * r;
  }
#pragma unroll
  for (int off = 32; off > 0; off >>= 1) {
    sum += __shfl_down(sum, off);
    sumsq += __shfl_down(sumsq, off);
  }
  int wave = threadIdx.x >> 6, lane = threadIdx.x & 63;
  if (lane == 0) { red[wave] = sum; red[4 + wave] = sumsq; }
  __syncthreads();
  if (threadIdx.x == 0) {
    float s0 = red[0] + red[1] + red[2] + red[3];
    float q0 = red[4] + red[5] + red[6] + red[7];
    float mu = s0 * (1.0f / 2048.0f);
    stats[0] = mu;
    stats[1] = rsqrtf(q0 * (1.0f / 2048.0f) - mu * mu + 1e-5f);
  }
  __syncthreads();
  float mu = stats[0], istd = stats[1];
  // output: out[bl][e in half][pos] = (R[e][(u+v)&31]-mu)*istd*lnw+lnb+x
  const float4* x4 = (const float4*)x;
  const float4* lw4 = (const float4*)lnw;
  const float4* lb4 = (const float4*)lnb;
  float4* o4 = (float4*)out;
  int t = threadIdx.x;
  int u = t >> 3, v0 = (t & 7) * 4;
#pragma unroll 4
  for (int it = 0; it < 32; ++it) {
    int e = half * 32 + it;
    int gid = bl * 16384 + e * 256 + t;
    int rem = e * 256 + t;
    float4 xin = x4[gid];
    float4 lw = lw4[rem];
    float4 lb = lb4[rem];
    float4 o;
    o.x = (Rsh[e][(u + v0) & 31] - mu) * istd * lw.x + lb.x + xin.x;
    o.y = (Rsh[e][(u + v0 + 1) & 31] - mu) * istd * lw.y + lb.y + xin.y;
    o.z = (Rsh[e][(u + v0 + 2) & 31] - mu) * istd * lw.z + lb.z + xin.z;
    o.w = (Rsh[e][(u + v0 + 3) & 31] - mu) * istd * lw.w + lb.w + xin.w;
    o4[gid] = o;
  }
}

extern "C" void kernel_launch(void* const* d_in, const int* in_sizes, int n_in,
                              void* d_out, int out_size, void* d_ws, size_t ws_size,
                              hipStream_t stream) {
  const float* x          = (const float*)d_in[0];
  const float* mask       = (const float*)d_in[1];
  const float* params_log = (const float*)d_in[2];
  const float* Wb_r  = (const float*)d_in[3];
  const float* Wb_i  = (const float*)d_in[4];
  const float* bb_r  = (const float*)d_in[5];
  const float* bb_i  = (const float*)d_in[6];
  const float* Wp1_r = (const float*)d_in[7];
  const float* Wp1_i = (const float*)d_in[8];
  const float* bp1_r = (const float*)d_in[9];
  const float* bp1_i = (const float*)d_in[10];
  const float* Wp2_r = (const float*)d_in[11];
  const float* Wp2_i = (const float*)d_in[12];
  const float* bp2_r = (const float*)d_in[13];
  const float* bp2_i = (const float*)d_in[14];
  const float* Wc_r  = (const float*)d_in[15];
  const float* Wc_i  = (const float*)d_in[16];
  const float* bc_r  = (const float*)d_in[17];
  // d_in[18] = bc_i: dropped by .real
  const float* ln_w  = (const float*)d_in[19];
  const float* ln_b  = (const float*)d_in[20];
  float* ws  = (float*)d_ws;
  float* out = (float*)d_out;

  kA<<<2109, 256, 0, stream>>>(x, params_log, Wb_r, Wb_i, bb_r, bb_i,
                               Wp1_r, Wp1_i, Wp2_r, Wp2_i, Wc_r, Wc_i,
                               bp2_r, bp2_i, bc_r, ws);
  kBC<<<256, 256, 0, stream>>>(ws, mask, bp1_r, bp1_i);
  kDE<<<256, 256, 0, stream>>>(x, ln_w, ln_b, ws, out);
}

// Round 3
// 178.312 us; speedup vs baseline: 1.0845x; 1.0845x over previous
//
#include <hip/hip_runtime.h>

// Problem constants
static constexpr int BL = 128;          // B*L = 4*32
// ws layout (float offsets)
static constexpr int OFF_ARE  = 2048;     // A = Wp1*Wb, [96][64]
static constexpr int OFF_AIM  = 8192;
static constexpr int OFF_WRE  = 14336;    // Wcp = Wc*Wp2, [64][96]
static constexpr int OFF_WIM  = 20480;
static constexpr int OFF_LRE  = 26624;    // lambda, [96][32]
static constexpr int OFF_LIM  = 29696;
static constexpr int OFF_GAM  = 32768;    // gamma, [96][32]
static constexpr int OFF_BH0R = 35840;    // 1024*Wp1*bb, [96]
static constexpr int OFF_BH0I = 35936;
static constexpr int OFF_BRR  = 36032;    // Re(Wc*bp2)+bc_r, [64]
static constexpr int OFF_QF   = 36096;    // qF [8192 planes][32 h] cplx
static constexpr int OFF_Y    = 560384;   // S (post-scan) [128][96][32] cplx
static constexpr int OFF_R    = 1871104;  // R [128][64][32] real
static constexpr int OFF_ST   = 2133248;  // partial stats [128][4] (sum0,sq0,sum1,sq1)

// Fused: blocks [0,2048) do per-plane anti-diagonal sums + 32-pt DFT;
// blocks [2048, 2109) do the parameter precompute (independent work).
__global__ __launch_bounds__(256) void kA(
    const float* __restrict__ x,
    const float* __restrict__ params_log,
    const float* __restrict__ Wb_r, const float* __restrict__ Wb_i,
    const float* __restrict__ bb_r, const float* __restrict__ bb_i,
    const float* __restrict__ Wp1_r, const float* __restrict__ Wp1_i,
    const float* __restrict__ Wp2_r, const float* __restrict__ Wp2_i,
    const float* __restrict__ Wc_r, const float* __restrict__ Wc_i,
    const float* __restrict__ bp2_r, const float* __restrict__ bp2_i,
    const float* __restrict__ bc_r, float* __restrict__ ws) {
  if (blockIdx.x < 2048) {
    __shared__ float pl[4][1024];
    __shared__ float qsh[4][32];
    __shared__ float ct[32], st[32];
    int wave = threadIdx.x >> 6, lane = threadIdx.x & 63;
    if (threadIdx.x < 32) {
      float sv, cv;
      sincosf((float)threadIdx.x * 0.19634954084936207f, &sv, &cv);
      ct[threadIdx.x] = cv;
      st[threadIdx.x] = sv;
    }
    int plane = blockIdx.x * 4 + wave;  // < 8192
    const float4* xp = (const float4*)(x + (size_t)plane * 1024);
    float4* pl4 = (float4*)pl[wave];
#pragma unroll
    for (int j = 0; j < 4; ++j) pl4[j * 64 + lane] = xp[j * 64 + lane];
    __syncthreads();
    int s = lane & 31, halfw = lane >> 5;
    float acc = 0.f;
#pragma unroll
    for (int u0 = 0; u0 < 16; ++u0) {
      int u = halfw * 16 + u0;
      acc += pl[wave][u * 32 + ((s - u) & 31)];
    }
    acc += __shfl_xor(acc, 32);
    if (lane < 32) qsh[wave][lane] = acc;
    __syncthreads();
    int h = lane & 31;
    const float* T = (lane < 32) ? ct : st;
    float sum = 0.f;
    int m = 0;
#pragma unroll
    for (int s2 = 0; s2 < 32; ++s2) {
      sum += qsh[wave][s2] * T[m];
      m = (m + h) & 31;
    }
    if (lane >= 32) sum = -sum;  // imag part of e^{-i...}
    ws[OFF_QF + (size_t)plane * 64 + h * 2 + (lane < 32 ? 0 : 1)] = sum;
  } else {
    int tid = (int)(blockIdx.x - 2048) * 256 + threadIdx.x;
    if (tid < 3072) {
      int i = tid;  // c*32+h
      float nu = expf(params_log[i]);
      float th = expf(params_log[3072 + i]);
      float g  = expf(params_log[6144 + i]);
      float rr = expf(-nu);
      ws[OFF_LRE + i] = rr * cosf(th);
      ws[OFF_LIM + i] = rr * sinf(th);
      ws[OFF_GAM + i] = g;
    } else if (tid < 9216) {
      int i = tid - 3072;  // A[c][e]
      int c = i >> 6, e = i & 63;
      float are = 0.f, aim = 0.f;
      for (int k = 0; k < 96; ++k) {
        float pr = Wp1_r[c * 96 + k], pi = Wp1_i[c * 96 + k];
        float wr = Wb_r[k * 64 + e], wi = Wb_i[k * 64 + e];
        are += pr * wr - pi * wi;
        aim += pr * wi + pi * wr;
      }
      ws[OFF_ARE + i] = are;
      ws[OFF_AIM + i] = aim;
    } else if (tid < 15360) {
      int i = tid - 9216;  // Wcp[e][c]
      int e = i / 96, c = i - e * 96;
      float are = 0.f, aim = 0.f;
      for (int k = 0; k < 96; ++k) {
        float wr = Wc_r[e * 96 + k], wi = Wc_i[e * 96 + k];
        float pr = Wp2_r[k * 96 + c], pi = Wp2_i[k * 96 + c];
        are += wr * pr - wi * pi;
        aim += wr * pi + wi * pr;
      }
      ws[OFF_WRE + i] = are;
      ws[OFF_WIM + i] = aim;
    } else if (tid < 15456) {
      int c = tid - 15360;  // 1024 * (Wp1 . bb)[c]
      float re = 0.f, im = 0.f;
      for (int k = 0; k < 96; ++k) {
        float pr = Wp1_r[c * 96 + k], pi = Wp1_i[c * 96 + k];
        float br = bb_r[k], bi = bb_i[k];
        re += pr * br - pi * bi;
        im += pr * bi + pi * br;
      }
      ws[OFF_BH0R + c] = 1024.f * re;
      ws[OFF_BH0I + c] = 1024.f * im;
    } else if (tid < 15520) {
      int e = tid - 15456;  // Re(Wc . bp2)[e] + bc_r[e]
      float re = 0.f;
      for (int k = 0; k < 96; ++k)
        re += Wc_r[e * 96 + k] * bp2_r[k] - Wc_i[e * 96 + k] * bp2_i[k];
      ws[OFF_BRR + e] = re + bc_r[e];
    }
  }
}

// Fused mix1 + decay-scan. Block = (b, h, c-half): for fixed h the whole
// l x c plane depends only on the qF[b,:,:,h] slice (16 KB, LDS). Compute
// Y = gamma*(A qF + bias) into LDS, scan over l in LDS, write post-scan S.
__global__ __launch_bounds__(256) void kBC(float* __restrict__ ws,
                                           const float* __restrict__ mask,
                                           const float* __restrict__ bp1_r,
                                           const float* __restrict__ bp1_i) {
  __shared__ float qre[32][65], qim[32][65];   // [l][e], pad -> conflict-free
  __shared__ float Yre[48][33], Yim[48][33];   // [c_loc][l]
  __shared__ float msh[32];
  int b = blockIdx.x >> 6;           // 4
  int h = (blockIdx.x >> 1) & 31;    // 32
  int ch = blockIdx.x & 1;           // c-half: c in [ch*48, ch*48+48)
  const float2* qF2 = (const float2*)(ws + OFF_QF);
  for (int i = threadIdx.x; i < 2048; i += 256) {
    int l = i >> 6, e = i & 63;
    float2 v = qF2[(size_t)(b * 2048 + l * 64 + e) * 32 + h];
    qre[l][e] = v.x;
    qim[l][e] = v.y;
  }
  if (threadIdx.x < 32) msh[threadIdx.x] = mask[b * 32 + threadIdx.x];
  __syncthreads();
  // mix1: thread = (l = t&31, cg = t>>5); 6 c's per thread.
  int l = threadIdx.x & 31, cg = threadIdx.x >> 5;
  int cbase = ch * 48 + cg * 6;
  float yr[6] = {0.f, 0.f, 0.f, 0.f, 0.f, 0.f};
  float yi[6] = {0.f, 0.f, 0.f, 0.f, 0.f, 0.f};
#pragma unroll 8
  for (int e = 0; e < 64; ++e) {
    float qr = qre[l][e], qi_ = qim[l][e];
#pragma unroll
    for (int k = 0; k < 6; ++k) {
      int c = cbase + k;
      float ar = ws[OFF_ARE + c * 64 + e];
      float ai = ws[OFF_AIM + c * 64 + e];
      yr[k] += ar * qr - ai * qi_;
      yi[k] += ar * qi_ + ai * qr;
    }
  }
#pragma unroll
  for (int k = 0; k < 6; ++k) {
    int c = cbase + k;
    float re = yr[k] + bp1_r[c];
    float im = yi[k] + bp1_i[c];
    if (h == 0) { re += ws[OFF_BH0R + c]; im += ws[OFF_BH0I + c]; }
    float g = ws[OFF_GAM + c * 32 + h];
    Yre[cg * 6 + k][l] = g * re;
    Yim[cg * 6 + k][l] = g * im;
  }
  __syncthreads();
  // scan over l per chain c (48 chains, block-local), write S to global.
  if (threadIdx.x < 48) {
    int cl = threadIdx.x, c = ch * 48 + cl;
    float lr = ws[OFF_LRE + c * 32 + h], li = ws[OFF_LIM + c * 32 + h];
    float2* Sg = (float2*)(ws + OFF_Y);
    float sr = Yre[cl][0], si = Yim[cl][0];
    Sg[((size_t)(b * 32 + 0) * 96 + c) * 32 + h] = make_float2(sr, si);
    for (int l2 = 1; l2 < 32; ++l2) {
      float mk = msh[l2 - 1];
      float cr = mk * (lr * sr - li * si);
      float ci = mk * (lr * si + li * sr);
      sr = Yre[cl][l2] + cr;
      si = Yim[cl][l2] + ci;
      Sg[((size_t)(b * 32 + l2) * 96 + c) * 32 + h] = make_float2(sr, si);
    }
  }
}

// Fused mix2 + iDFT + R + partial LN stats. 2 blocks per bl (e-halves),
// V never leaves LDS. 256 blocks = full chip, ~33 KB LDS -> 4 blocks/CU.
__global__ __launch_bounds__(256) void kD(float* __restrict__ ws) {
  __shared__ float2 S[96][32];   // 24 KB
  __shared__ float2 V[32][33];   // padded: kills write bank conflicts
  __shared__ float ct[32], st[32];
  __shared__ float red[8];
  int bl = blockIdx.x >> 1, half = blockIdx.x & 1;
  const float2* Sg = (const float2*)(ws + OFF_Y) + (size_t)bl * 3072;
  for (int i = threadIdx.x; i < 3072; i += 256) S[i >> 5][i & 31] = Sg[i];
  if (threadIdx.x < 32) {
    float sv, cv;
    sincosf((float)threadIdx.x * 0.19634954084936207f, &sv, &cv);
    ct[threadIdx.x] = cv;
    st[threadIdx.x] = sv;
  }
  __syncthreads();
  // mix2: thread -> (e = half*32 + k*8 + g, h), hoisted S read shared by 4 e.
  int h = threadIdx.x & 31, g = threadIdx.x >> 5;
  float vr[4] = {0.f, 0.f, 0.f, 0.f}, vi[4] = {0.f, 0.f, 0.f, 0.f};
  int ebase = half * 32 + g;
#pragma unroll 4
  for (int c = 0; c < 96; ++c) {
    float2 s = S[c][h];
#pragma unroll
    for (int k = 0; k < 4; ++k) {
      int e = ebase + k * 8;
      float wr = ws[OFF_WRE + e * 96 + c];
      float wi = ws[OFF_WIM + e * 96 + c];
      vr[k] += wr * s.x - wi * s.y;
      vi[k] += wr * s.y + wi * s.x;
    }
  }
#pragma unroll
  for (int k = 0; k < 4; ++k) V[k * 8 + g][h] = make_float2(vr[k], vi[k]);
  __syncthreads();
  // iDFT: R[e,s] = Re(sum_h V[e,h] e^{+i..})/1024 + bR[e]; stats.
  float* R = ws + OFF_R + bl * 2048 + half * 1024;
  float sum = 0.f, sumsq = 0.f;
#pragma unroll
  for (int k = 0; k < 4; ++k) {
    int idx = k * 256 + threadIdx.x;
    int el = idx >> 5, s2 = idx & 31;
    float acc = 0.f;
    int m = 0;
#pragma unroll
    for (int hh = 0; hh < 32; ++hh) {
      float2 v = V[el][hh];
      acc += v.x * ct[m] - v.y * st[m];
      m = (m + s2) & 31;
    }
    float r = acc * (1.0f / 1024.0f) + ws[OFF_BRR + half * 32 + el];
    R[idx] = r;
    sum += r;
    sumsq += r * r;
  }
#pragma unroll
  for (int off = 32; off > 0; off >>= 1) {
    sum += __shfl_down(sum, off);
    sumsq += __shfl_down(sumsq, off);
  }
  int wave = threadIdx.x >> 6, lane = threadIdx.x & 63;
  if (lane == 0) { red[wave] = sum; red[4 + wave] = sumsq; }
  __syncthreads();
  if (threadIdx.x == 0) {
    ws[OFF_ST + bl * 4 + half * 2]     = red[0] + red[1] + red[2] + red[3];
    ws[OFF_ST + bl * 4 + half * 2 + 1] = red[4] + red[5] + red[6] + red[7];
  }
}

// out = (R[bl,e,(u+v)&31]-mu)*istd*ln_w + ln_b + x. One block == one (bl,e)
// plane; R row staged in LDS. 8192 blocks -> full occupancy, BW-bound.
__global__ __launch_bounds__(256) void kE(const float* __restrict__ x,
                                          const float* __restrict__ lnw,
                                          const float* __restrict__ lnb,
                                          const float* __restrict__ ws,
                                          float* __restrict__ out) {
  __shared__ float Rs[32];
  int bl = blockIdx.x >> 6, e = blockIdx.x & 63;
  if (threadIdx.x < 32)
    Rs[threadIdx.x] = ws[OFF_R + bl * 2048 + e * 32 + threadIdx.x];
  const float* stp = ws + OFF_ST + bl * 4;
  float s0 = stp[0] + stp[2], q0 = stp[1] + stp[3];
  float mu = s0 * (1.0f / 2048.0f);
  float istd = rsqrtf(q0 * (1.0f / 2048.0f) - mu * mu + 1e-5f);
  __syncthreads();
  int gid = blockIdx.x * 256 + threadIdx.x;
  int pos = threadIdx.x * 4;  // < 1024
  int u = pos >> 5, v = pos & 31;
  int rem4 = e * 256 + threadIdx.x;  // float4 index into lnw/lnb
  const float4 xin = ((const float4*)x)[gid];
  const float4 lw = ((const float4*)lnw)[rem4];
  const float4 lb = ((const float4*)lnb)[rem4];
  float4 o;
  o.x = (Rs[(u + v) & 31] - mu) * istd * lw.x + lb.x + xin.x;
  o.y = (Rs[(u + v + 1) & 31] - mu) * istd * lw.y + lb.y + xin.y;
  o.z = (Rs[(u + v + 2) & 31] - mu) * istd * lw.z + lb.z + xin.z;
  o.w = (Rs[(u + v + 3) & 31] - mu) * istd * lw.w + lb.w + xin.w;
  ((float4*)out)[gid] = o;
}

extern "C" void kernel_launch(void* const* d_in, const int* in_sizes, int n_in,
                              void* d_out, int out_size, void* d_ws, size_t ws_size,
                              hipStream_t stream) {
  const float* x          = (const float*)d_in[0];
  const float* mask       = (const float*)d_in[1];
  const float* params_log = (const float*)d_in[2];
  const float* Wb_r  = (const float*)d_in[3];
  const float* Wb_i  = (const float*)d_in[4];
  const float* bb_r  = (const float*)d_in[5];
  const float* bb_i  = (const float*)d_in[6];
  const float* Wp1_r = (const float*)d_in[7];
  const float* Wp1_i = (const float*)d_in[8];
  const float* bp1_r = (const float*)d_in[9];
  const float* bp1_i = (const float*)d_in[10];
  const float* Wp2_r = (const float*)d_in[11];
  const float* Wp2_i = (const float*)d_in[12];
  const float* bp2_r = (const float*)d_in[13];
  const float* bp2_i = (const float*)d_in[14];
  const float* Wc_r  = (const float*)d_in[15];
  const float* Wc_i  = (const float*)d_in[16];
  const float* bc_r  = (const float*)d_in[17];
  // d_in[18] = bc_i: dropped by .real
  const float* ln_w  = (const float*)d_in[19];
  const float* ln_b  = (const float*)d_in[20];
  float* ws  = (float*)d_ws;
  float* out = (float*)d_out;

  kA<<<2109, 256, 0, stream>>>(x, params_log, Wb_r, Wb_i, bb_r, bb_i,
                               Wp1_r, Wp1_i, Wp2_r, Wp2_i, Wc_r, Wc_i,
                               bp2_r, bp2_i, bc_r, ws);
  kBC<<<256, 256, 0, stream>>>(ws, mask, bp1_r, bp1_i);
  kD<<<256, 256, 0, stream>>>(ws);
  kE<<<8192, 256, 0, stream>>>(x, ln_w, ln_b, ws, out);
}

// Round 5
// 169.204 us; speedup vs baseline: 1.1428x; 1.0538x over previous
//
#include <hip/hip_runtime.h>

// Problem constants
static constexpr int BL = 128;          // B*L = 4*32
// ws layout (float offsets)
static constexpr int OFF_ARE  = 2048;     // A = Wp1*Wb, [96][64]
static constexpr int OFF_AIM  = 8192;
static constexpr int OFF_WRE  = 14336;    // Wcp = Wc*Wp2, [64][96]
static constexpr int OFF_WIM  = 20480;
static constexpr int OFF_LRE  = 26624;    // lambda, [96][32]
static constexpr int OFF_LIM  = 29696;
static constexpr int OFF_GAM  = 32768;    // gamma, [96][32]
static constexpr int OFF_BH0R = 35840;    // 1024*Wp1*bb, [96]
static constexpr int OFF_BH0I = 35936;
static constexpr int OFF_BRR  = 36032;    // Re(Wc*bp2)+bc_r, [64]
static constexpr int OFF_QF   = 36096;    // qF [8192 planes][32 h] cplx
static constexpr int OFF_Y    = 560384;   // Y/S [128][96][32] cplx
static constexpr int OFF_R    = 1871104;  // R [128][64][32] real
static constexpr int OFF_ST   = 2133248;  // partial stats [128][4] (sum0,sq0,sum1,sq1)

// Fused: blocks [0,2048) do per-plane anti-diagonal sums + 32-pt DFT;
// blocks [2048, 2109) do the parameter precompute (independent work).
__global__ __launch_bounds__(256) void kA(
    const float* __restrict__ x,
    const float* __restrict__ params_log,
    const float* __restrict__ Wb_r, const float* __restrict__ Wb_i,
    const float* __restrict__ bb_r, const float* __restrict__ bb_i,
    const float* __restrict__ Wp1_r, const float* __restrict__ Wp1_i,
    const float* __restrict__ Wp2_r, const float* __restrict__ Wp2_i,
    const float* __restrict__ Wc_r, const float* __restrict__ Wc_i,
    const float* __restrict__ bp2_r, const float* __restrict__ bp2_i,
    const float* __restrict__ bc_r, float* __restrict__ ws) {
  if (blockIdx.x < 2048) {
    __shared__ float pl[4][1024];
    __shared__ float qsh[4][32];
    __shared__ float ct[32], st[32];
    int wave = threadIdx.x >> 6, lane = threadIdx.x & 63;
    if (threadIdx.x < 32) {
      float sv, cv;
      sincosf((float)threadIdx.x * 0.19634954084936207f, &sv, &cv);
      ct[threadIdx.x] = cv;
      st[threadIdx.x] = sv;
    }
    int plane = blockIdx.x * 4 + wave;  // < 8192
    const float4* xp = (const float4*)(x + (size_t)plane * 1024);
    float4* pl4 = (float4*)pl[wave];
#pragma unroll
    for (int j = 0; j < 4; ++j) pl4[j * 64 + lane] = xp[j * 64 + lane];
    __syncthreads();
    int s = lane & 31, halfw = lane >> 5;
    float acc = 0.f;
#pragma unroll
    for (int u0 = 0; u0 < 16; ++u0) {
      int u = halfw * 16 + u0;
      acc += pl[wave][u * 32 + ((s - u) & 31)];
    }
    acc += __shfl_xor(acc, 32);
    if (lane < 32) qsh[wave][lane] = acc;
    __syncthreads();
    int h = lane & 31;
    const float* T = (lane < 32) ? ct : st;
    float sum = 0.f;
    int m = 0;
#pragma unroll
    for (int s2 = 0; s2 < 32; ++s2) {
      sum += qsh[wave][s2] * T[m];
      m = (m + h) & 31;
    }
    if (lane >= 32) sum = -sum;  // imag part of e^{-i...}
    ws[OFF_QF + (size_t)plane * 64 + h * 2 + (lane < 32 ? 0 : 1)] = sum;
  } else {
    int tid = (int)(blockIdx.x - 2048) * 256 + threadIdx.x;
    if (tid < 3072) {
      int i = tid;  // c*32+h
      float nu = expf(params_log[i]);
      float th = expf(params_log[3072 + i]);
      float g  = expf(params_log[6144 + i]);
      float rr = expf(-nu);
      ws[OFF_LRE + i] = rr * cosf(th);
      ws[OFF_LIM + i] = rr * sinf(th);
      ws[OFF_GAM + i] = g;
    } else if (tid < 9216) {
      int i = tid - 3072;  // A[c][e]
      int c = i >> 6, e = i & 63;
      float are = 0.f, aim = 0.f;
      for (int k = 0; k < 96; ++k) {
        float pr = Wp1_r[c * 96 + k], pi = Wp1_i[c * 96 + k];
        float wr = Wb_r[k * 64 + e], wi = Wb_i[k * 64 + e];
        are += pr * wr - pi * wi;
        aim += pr * wi + pi * wr;
      }
      ws[OFF_ARE + i] = are;
      ws[OFF_AIM + i] = aim;
    } else if (tid < 15360) {
      int i = tid - 9216;  // Wcp[e][c]
      int e = i / 96, c = i - e * 96;
      float are = 0.f, aim = 0.f;
      for (int k = 0; k < 96; ++k) {
        float wr = Wc_r[e * 96 + k], wi = Wc_i[e * 96 + k];
        float pr = Wp2_r[k * 96 + c], pi = Wp2_i[k * 96 + c];
        are += wr * pr - wi * pi;
        aim += wr * pi + wi * pr;
      }
      ws[OFF_WRE + i] = are;
      ws[OFF_WIM + i] = aim;
    } else if (tid < 15456) {
      int c = tid - 15360;  // 1024 * (Wp1 . bb)[c]
      float re = 0.f, im = 0.f;
      for (int k = 0; k < 96; ++k) {
        float pr = Wp1_r[c * 96 + k], pi = Wp1_i[c * 96 + k];
        float br = bb_r[k], bi = bb_i[k];
        re += pr * br - pi * bi;
        im += pr * bi + pi * br;
      }
      ws[OFF_BH0R + c] = 1024.f * re;
      ws[OFF_BH0I + c] = 1024.f * im;
    } else if (tid < 15520) {
      int e = tid - 15456;  // Re(Wc . bp2)[e] + bc_r[e]
      float re = 0.f;
      for (int k = 0; k < 96; ++k)
        re += Wc_r[e * 96 + k] * bp2_r[k] - Wc_i[e * 96 + k] * bp2_i[k];
      ws[OFF_BRR + e] = re + bc_r[e];
    }
  }
}

// Y[bl,c,h] = gamma * (sum_e A[c,e]*qF[bl,e,h] + bh0*d(h==0) + bp1)
// 1536 blocks (12 c-chunks x 128 bl), coalesced qF staging -> 6 blocks/CU.
__global__ __launch_bounds__(256) void kB(float* __restrict__ ws,
                                          const float* __restrict__ bp1_r,
                                          const float* __restrict__ bp1_i) {
  __shared__ float2 q[64][32];
  int bl = blockIdx.x / 12, chunk = blockIdx.x % 12;
  const float2* qF = (const float2*)(ws + OFF_QF) + bl * 2048;
  for (int i = threadIdx.x; i < 2048; i += 256) q[i >> 5][i & 31] = qF[i];
  __syncthreads();
  int c = chunk * 8 + (threadIdx.x >> 5), h = threadIdx.x & 31;
  const float* Ar = ws + OFF_ARE + c * 64;
  const float* Ai = ws + OFF_AIM + c * 64;
  float re = 0.f, im = 0.f;
#pragma unroll 8
  for (int e = 0; e < 64; ++e) {
    float ar = Ar[e], ai = Ai[e];
    float2 qv = q[e][h];
    re += ar * qv.x - ai * qv.y;
    im += ar * qv.y + ai * qv.x;
  }
  if (h == 0) { re += ws[OFF_BH0R + c]; im += ws[OFF_BH0I + c]; }
  re += bp1_r[c];
  im += bp1_i[c];
  float g = ws[OFF_GAM + c * 32 + h];
  ((float2*)(ws + OFF_Y))[(bl * 96 + c) * 32 + h] = make_float2(g * re, g * im);
}

// Sequential decay scan over L=32 per (b,c,h) — all loads prefetched into
// registers (independent), scan in-register, store back. 192 CUs active.
// Mask preloaded into registers (wave-uniform scalar loads, off the chain).
__global__ __launch_bounds__(64) void kC(float* __restrict__ ws,
                                         const float* __restrict__ mask) {
  int tid = blockIdx.x * 64 + threadIdx.x;  // < 12288 chains
  int b = tid / 3072, r = tid - b * 3072;   // r = c*32+h (b uniform per block)
  float lr = ws[OFF_LRE + r], li = ws[OFF_LIM + r];
  float mk[31];
#pragma unroll
  for (int l = 0; l < 31; ++l) mk[l] = mask[b * 32 + l];
  float2* Y = (float2*)(ws + OFF_Y) + (size_t)b * 3072 * 32 + r;
  float2 v[32];
#pragma unroll
  for (int l = 0; l < 32; ++l) v[l] = Y[(size_t)l * 3072];
  float sr = v[0].x, si = v[0].y;
#pragma unroll
  for (int l = 1; l < 32; ++l) {
    float cr = mk[l - 1] * (lr * sr - li * si);
    float ci = mk[l - 1] * (lr * si + li * sr);
    sr = v[l].x + cr;
    si = v[l].y + ci;
    v[l] = make_float2(sr, si);
  }
#pragma unroll
  for (int l = 1; l < 32; ++l) Y[(size_t)l * 3072] = v[l];
}

// Fused mix2 + iDFT + R + partial LN stats. 2 blocks per bl (e-halves),
// V never leaves LDS. 256 blocks, ~33 KB LDS.
__global__ __launch_bounds__(256) void kD(float* __restrict__ ws) {
  __shared__ float2 S[96][32];   // 24 KB
  __shared__ float2 V[32][33];   // padded: kills write bank conflicts
  __shared__ float ct[32], st[32];
  __shared__ float red[8];
  int bl = blockIdx.x >> 1, half = blockIdx.x & 1;
  const float2* Sg = (const float2*)(ws + OFF_Y) + (size_t)bl * 3072;
  for (int i = threadIdx.x; i < 3072; i += 256) S[i >> 5][i & 31] = Sg[i];
  if (threadIdx.x < 32) {
    float sv, cv;
    sincosf((float)threadIdx.x * 0.19634954084936207f, &sv, &cv);
    ct[threadIdx.x] = cv;
    st[threadIdx.x] = sv;
  }
  __syncthreads();
  // mix2: thread -> (e = half*32 + k*8 + g, h), hoisted S read shared by 4 e.
  int h = threadIdx.x & 31, g = threadIdx.x >> 5;
  float vr[4] = {0.f, 0.f, 0.f, 0.f}, vi[4] = {0.f, 0.f, 0.f, 0.f};
  int ebase = half * 32 + g;
#pragma unroll 4
  for (int c = 0; c < 96; ++c) {
    float2 s = S[c][h];
#pragma unroll
    for (int k = 0; k < 4; ++k) {
      int e = ebase + k * 8;
      float wr = ws[OFF_WRE + e * 96 + c];
      float wi = ws[OFF_WIM + e * 96 + c];
      vr[k] += wr * s.x - wi * s.y;
      vi[k] += wr * s.y + wi * s.x;
    }
  }
#pragma unroll
  for (int k = 0; k < 4; ++k) V[k * 8 + g][h] = make_float2(vr[k], vi[k]);
  __syncthreads();
  // iDFT: R[e,s] = Re(sum_h V[e,h] e^{+i..})/1024 + bR[e]; stats.
  float* R = ws + OFF_R + bl * 2048 + half * 1024;
  float sum = 0.f, sumsq = 0.f;
#pragma unroll
  for (int k = 0; k < 4; ++k) {
    int idx = k * 256 + threadIdx.x;
    int el = idx >> 5, s2 = idx & 31;
    float acc = 0.f;
    int m = 0;
#pragma unroll
    for (int hh = 0; hh < 32; ++hh) {
      float2 v = V[el][hh];
      acc += v.x * ct[m] - v.y * st[m];
      m = (m + s2) & 31;
    }
    float r = acc * (1.0f / 1024.0f) + ws[OFF_BRR + half * 32 + el];
    R[idx] = r;
    sum += r;
    sumsq += r * r;
  }
#pragma unroll
  for (int off = 32; off > 0; off >>= 1) {
    sum += __shfl_down(sum, off);
    sumsq += __shfl_down(sumsq, off);
  }
  int wave = threadIdx.x >> 6, lane = threadIdx.x & 63;
  if (lane == 0) { red[wave] = sum; red[4 + wave] = sumsq; }
  __syncthreads();
  if (threadIdx.x == 0) {
    ws[OFF_ST + bl * 4 + half * 2]     = red[0] + red[1] + red[2] + red[3];
    ws[OFF_ST + bl * 4 + half * 2 + 1] = red[4] + red[5] + red[6] + red[7];
  }
}

// out = (R[bl,e,(u+v)&31]-mu)*istd*ln_w + ln_b + x. One block == one (bl,e)
// plane; R row staged in LDS. 8192 blocks -> full occupancy, BW-bound.
__global__ __launch_bounds__(256) void kE(const float* __restrict__ x,
                                          const float* __restrict__ lnw,
                                          const float* __restrict__ lnb,
                                          const float* __restrict__ ws,
                                          float* __restrict__ out) {
  __shared__ float Rs[32];
  int bl = blockIdx.x >> 6, e = blockIdx.x & 63;
  if (threadIdx.x < 32)
    Rs[threadIdx.x] = ws[OFF_R + bl * 2048 + e * 32 + threadIdx.x];
  const float* stp = ws + OFF_ST + bl * 4;
  float s0 = stp[0] + stp[2], q0 = stp[1] + stp[3];
  float mu = s0 * (1.0f / 2048.0f);
  float istd = rsqrtf(q0 * (1.0f / 2048.0f) - mu * mu + 1e-5f);
  __syncthreads();
  int gid = blockIdx.x * 256 + threadIdx.x;
  int pos = threadIdx.x * 4;  // < 1024
  int u = pos >> 5, v = pos & 31;
  int rem4 = e * 256 + threadIdx.x;  // float4 index into lnw/lnb
  const float4 xin = ((const float4*)x)[gid];
  const float4 lw = ((const float4*)lnw)[rem4];
  const float4 lb = ((const float4*)lnb)[rem4];
  float4 o;
  o.x = (Rs[(u + v) & 31] - mu) * istd * lw.x + lb.x + xin.x;
  o.y = (Rs[(u + v + 1) & 31] - mu) * istd * lw.y + lb.y + xin.y;
  o.z = (Rs[(u + v + 2) & 31] - mu) * istd * lw.z + lb.z + xin.z;
  o.w = (Rs[(u + v + 3) & 31] - mu) * istd * lw.w + lb.w + xin.w;
  ((float4*)out)[gid] = o;
}

extern "C" void kernel_launch(void* const* d_in, const int* in_sizes, int n_in,
                              void* d_out, int out_size, void* d_ws, size_t ws_size,
                              hipStream_t stream) {
  const float* x          = (const float*)d_in[0];
  const float* mask       = (const float*)d_in[1];
  const float* params_log = (const float*)d_in[2];
  const float* Wb_r  = (const float*)d_in[3];
  const float* Wb_i  = (const float*)d_in[4];
  const float* bb_r  = (const float*)d_in[5];
  const float* bb_i  = (const float*)d_in[6];
  const float* Wp1_r = (const float*)d_in[7];
  const float* Wp1_i = (const float*)d_in[8];
  const float* bp1_r = (const float*)d_in[9];
  const float* bp1_i = (const float*)d_in[10];
  const float* Wp2_r = (const float*)d_in[11];
  const float* Wp2_i = (const float*)d_in[12];
  const float* bp2_r = (const float*)d_in[13];
  const float* bp2_i = (const float*)d_in[14];
  const float* Wc_r  = (const float*)d_in[15];
  const float* Wc_i  = (const float*)d_in[16];
  const float* bc_r  = (const float*)d_in[17];
  // d_in[18] = bc_i: dropped by .real
  const float* ln_w  = (const float*)d_in[19];
  const float* ln_b  = (const float*)d_in[20];
  float* ws  = (float*)d_ws;
  float* out = (float*)d_out;

  kA<<<2109, 256, 0, stream>>>(x, params_log, Wb_r, Wb_i, bb_r, bb_i,
                               Wp1_r, Wp1_i, Wp2_r, Wp2_i, Wc_r, Wc_i,
                               bp2_r, bp2_i, bc_r, ws);
  kB<<<1536, 256, 0, stream>>>(ws, bp1_r, bp1_i);
  kC<<<192, 64, 0, stream>>>(ws, mask);
  kD<<<256, 256, 0, stream>>>(ws);
  kE<<<8192, 256, 0, stream>>>(x, ln_w, ln_b, ws, out);
}